// Round 6
// baseline (510.573 us; speedup 1.0000x reference)
//
#include <hip/hip_runtime.h>
#include <math.h>

#define BB 4
#define SS 1024
#define DD 768
#define HH 12
#define DHH 64

typedef __attribute__((ext_vector_type(8))) short bf16x8;   // 8 bf16 = 4 VGPR
typedef __attribute__((ext_vector_type(4))) float f32x4;    // MFMA acc

__device__ __forceinline__ unsigned int f2bf(float f) {
    unsigned int u = __float_as_uint(f);
    return (u + 0x7FFFu + ((u >> 16) & 1u)) >> 16;   // RNE
}
__device__ __forceinline__ float bf2f(unsigned int h) {
    return __uint_as_float(h << 16);
}

// async global->LDS, 16B per lane. dest must be wave-uniform base (+lane*16 by HW).
__device__ __forceinline__ void glds16(const void* g, void* l) {
    __builtin_amdgcn_global_load_lds(
        (const __attribute__((address_space(1))) void*)g,
        (__attribute__((address_space(3))) void*)l, 16, 0, 0);
}

// ======================================================================
// prep: fp32 -> bf16 convert of hidden
// ======================================================================
__global__ __launch_bounds__(256)
void cvt_hidden_kernel(const float* __restrict__ src, unsigned short* __restrict__ dst)
{
    const int idx = (blockIdx.x * 256 + threadIdx.x) * 8;
    float4 a = *(const float4*)&src[idx];
    float4 b = *(const float4*)&src[idx + 4];
    uint4 p;
    p.x = f2bf(a.x) | (f2bf(a.y) << 16);
    p.y = f2bf(a.z) | (f2bf(a.w) << 16);
    p.z = f2bf(b.x) | (f2bf(b.y) << 16);
    p.w = f2bf(b.z) | (f2bf(b.w) << 16);
    *(uint4*)&dst[idx] = p;
}

// ======================================================================
// prep: W[k][n] fp32 -> Wt[w][n][k] bf16 (transposed, n-major)
// ======================================================================
__global__ __launch_bounds__(256)
void transpose_w_kernel(const float* __restrict__ Wq, const float* __restrict__ Wk,
                        const float* __restrict__ Wv, const float* __restrict__ Wo,
                        unsigned short* __restrict__ Wt)
{
    __shared__ float tile[32][33];
    const int t = threadIdx.x;
    const int kt = blockIdx.x, nt = blockIdx.y, w = blockIdx.z;
    const float* src = (w == 0) ? Wq : (w == 1) ? Wk : (w == 2) ? Wv : Wo;
    const int r = t >> 3, c4 = (t & 7) * 4;
    float4 v = *(const float4*)&src[(kt * 32 + r) * DD + nt * 32 + c4];
    tile[r][c4 + 0] = v.x; tile[r][c4 + 1] = v.y;
    tile[r][c4 + 2] = v.z; tile[r][c4 + 3] = v.w;
    __syncthreads();
    uint2 p;
    p.x = f2bf(tile[c4 + 0][r]) | (f2bf(tile[c4 + 1][r]) << 16);
    p.y = f2bf(tile[c4 + 2][r]) | (f2bf(tile[c4 + 3][r]) << 16);
    *(uint2*)&Wt[((size_t)w * DD + nt * 32 + r) * DD + kt * 32 + c4] = p;
}

// ======================================================================
// shared MFMA GEMM core: 64x64 tile, K=768 in 12 chunks of 64.
// ======================================================================
__device__ __forceinline__ void gemm_core64(
    const char* __restrict__ Ag, const char* __restrict__ Bg,
    char* As, char* Bs, int tid, f32x4 (&acc)[2][2])
{
    const int lane = tid & 63;
    const int wr = (tid >> 7) & 1;
    const int wc = (tid >> 6) & 1;
    const int ldst = (tid & 192) << 4;

    for (int c = 0; c < 12; ++c) {
        const int kbyte = c * 128;
        #pragma unroll
        for (int i = 0; i < 2; ++i) {
            const int s = i * 256 + tid;
            const int row = s >> 3, kb = s & 7;
            const size_t off = (size_t)row * 1536 + kbyte + ((kb ^ (row & 7)) << 4);
            glds16(Ag + off, As + i * 4096 + ldst);
            glds16(Bg + off, Bs + i * 4096 + ldst);
        }
        __syncthreads();
        #pragma unroll
        for (int ks = 0; ks < 2; ++ks) {
            const int kb = ks * 4 + (lane >> 4);
            bf16x8 a[2], b[2];
            #pragma unroll
            for (int mi = 0; mi < 2; ++mi) {
                const int row = wr * 32 + mi * 16 + (lane & 15);
                a[mi] = *(const bf16x8*)(As + row * 128 + ((kb ^ (row & 7)) << 4));
            }
            #pragma unroll
            for (int ni = 0; ni < 2; ++ni) {
                const int row = wc * 32 + ni * 16 + (lane & 15);
                b[ni] = *(const bf16x8*)(Bs + row * 128 + ((kb ^ (row & 7)) << 4));
            }
            #pragma unroll
            for (int mi = 0; mi < 2; ++mi)
                #pragma unroll
                for (int ni = 0; ni < 2; ++ni)
                    acc[mi][ni] = __builtin_amdgcn_mfma_f32_16x16x32_bf16(
                        a[mi], b[ni], acc[mi][ni], 0, 0, 0);
        }
        __syncthreads();
    }
}

// ======================================================================
// QKV projection. Q,K -> bf16 [B,H,S,DH]; V -> bf16 [B,H,DH,S].
// ======================================================================
__global__ __launch_bounds__(256)
void qkv_gemm_kernel(const unsigned short* __restrict__ hbf, const unsigned short* __restrict__ Wt,
                     const float* __restrict__ bq, const float* __restrict__ bk,
                     const float* __restrict__ bv,
                     unsigned short* __restrict__ Qb, unsigned short* __restrict__ Kb,
                     unsigned short* __restrict__ Vtb)
{
    __shared__ __align__(16) char As[8192];
    __shared__ __align__(16) char Bs[8192];
    const int tid = threadIdx.x;
    const int m0 = blockIdx.x * 64;
    const int w = blockIdx.y / 12;
    const int n0w = (blockIdx.y % 12) * 64;

    f32x4 acc[2][2];
    const f32x4 z4 = {0.f, 0.f, 0.f, 0.f};
    acc[0][0] = z4; acc[0][1] = z4; acc[1][0] = z4; acc[1][1] = z4;

    const char* Ag = (const char*)hbf + (size_t)m0 * 1536;
    const char* Bg = (const char*)Wt + ((size_t)w * DD + n0w) * 1536;
    gemm_core64(Ag, Bg, As, Bs, tid, acc);

    const int lane = tid & 63;
    const int wr = (tid >> 7) & 1, wc = (tid >> 6) & 1;
    const int b = m0 >> 10, s0 = m0 & 1023;
    const int h = n0w >> 6;
    const float* bias = (w == 0) ? bq : (w == 1) ? bk : bv;

    if (w == 2) {
        #pragma unroll
        for (int mi = 0; mi < 2; ++mi)
            #pragma unroll
            for (int ni = 0; ni < 2; ++ni) {
                const int drow = wc * 32 + ni * 16 + (lane & 15);
                const float bb = bias[n0w + drow];
                #pragma unroll
                for (int r = 0; r < 4; ++r) {
                    const int scol = wr * 32 + mi * 16 + (lane >> 4) * 4 + r;
                    const int byte = (drow * 128 + scol * 2) ^ ((drow & 7) << 4);
                    *(unsigned short*)(As + byte) = (unsigned short)f2bf(acc[mi][ni][r] + bb);
                }
            }
        __syncthreads();
        const int drow = tid >> 2, c32 = (tid & 3) * 32;
        const int sw = (drow & 7) << 4;
        uint4 lo = *(uint4*)(As + ((drow * 128 + c32) ^ sw));
        uint4 hi = *(uint4*)(As + ((drow * 128 + c32 + 16) ^ sw));
        char* dst = (char*)Vtb + ((((size_t)(b * HH + h) * DHH) + drow) * SS + s0) * 2 + c32;
        *(uint4*)dst = lo; *(uint4*)(dst + 16) = hi;
    } else {
        #pragma unroll
        for (int mi = 0; mi < 2; ++mi)
            #pragma unroll
            for (int ni = 0; ni < 2; ++ni) {
                const int ncol = wc * 32 + ni * 16 + (lane & 15);
                const float bb = bias[n0w + ncol];
                #pragma unroll
                for (int r = 0; r < 4; ++r) {
                    const int srow = wr * 32 + mi * 16 + (lane >> 4) * 4 + r;
                    const int byte = (srow * 128 + ncol * 2) ^ ((srow & 7) << 4);
                    *(unsigned short*)(As + byte) = (unsigned short)f2bf(acc[mi][ni][r] + bb);
                }
            }
        __syncthreads();
        const int srow = tid >> 2, c32 = (tid & 3) * 32;
        const int sw = (srow & 7) << 4;
        uint4 lo = *(uint4*)(As + ((srow * 128 + c32) ^ sw));
        uint4 hi = *(uint4*)(As + ((srow * 128 + c32 + 16) ^ sw));
        unsigned short* base = (w == 0) ? Qb : Kb;
        char* dst = (char*)base + (((size_t)(b * HH + h) * SS + s0 + srow) * DHH) * 2 + c32;
        *(uint4*)dst = lo; *(uint4*)(dst + 16) = hi;
    }
}

// ======================================================================
// FUSED attention: block = (b, 16 q rows), 768 threads = 12 waves = 12 heads.
// Pass 1: QK^T (MFMA, K direct-global) -> Z1 in regs.
// Pass 2 per 64-k tile:
//   A) wave h: recompute QK^T -> p1 = e1*invZ1 -> bf16 into own 2KB LDS slice
//   B) coop (q,k4,hgrp): prev direct-global float4, conv mix + e2 (4 heads),
//      write e2 in place; z2 partials in regs
//   C) wave h: read A-frags from own slice, PV MFMA vs direct-global V
// Epilogue: z2 exchange via LDS, divide, per-wave repack, coalesced store.
// ======================================================================
__global__ __launch_bounds__(768)
void fused_attn_kernel(const unsigned short* __restrict__ Qb, const unsigned short* __restrict__ Kb,
                       const unsigned short* __restrict__ Vtb, const float* __restrict__ prev,
                       const float* __restrict__ mask, const float* __restrict__ cw,
                       const float* __restrict__ cb, unsigned short* __restrict__ ctx)
{
    __shared__ __align__(16) char Pbuf[24576];   // 12 slices x [16q][64k] bf16 swizzled
    __shared__ float cws[144], cbs[12];
    __shared__ float z2buf[12][16];

    const int tid  = threadIdx.x;
    const int lane = tid & 63;
    const int w    = tid >> 6;          // wave = head, 0..11
    const int b    = blockIdx.x >> 6;
    const int q0   = (blockIdx.x & 63) * 16;

    if (tid < 144) cws[tid] = cw[tid];
    if (tid < 12)  cbs[tid] = cb[tid];

    // B-role indices
    const int slot = tid & 255;
    const int hgrp = tid >> 8;          // 0..2
    const int qB   = slot >> 4;         // 0..15
    const int k4   = slot & 15;         // k = k4*4..+3 within tile

    // Q A-frags for wave's 16 q rows (held all kernel)
    const char* Qrow = (const char*)Qb + (((size_t)(b * HH + w) * SS) + q0 + (lane & 15)) * 128;
    const bf16x8 aq0 = *(const bf16x8*)(Qrow + (lane >> 4) * 16);
    const bf16x8 aq1 = *(const bf16x8*)(Qrow + 64 + (lane >> 4) * 16);

    const char* Kbase = (const char*)Kb + (size_t)(b * HH + w) * SS * 128;
    const char* Vbase = (const char*)Vtb + (size_t)(b * HH + w) * DHH * 2048;

    __syncthreads();   // cws/cbs visible

    // ---------------- pass 1: Z1 ----------------
    float zr[4] = {0.f, 0.f, 0.f, 0.f};
    for (int kt = 0; kt < 16; ++kt) {
        #pragma unroll
        for (int nf = 0; nf < 4; ++nf) {
            const int krow = kt * 64 + nf * 16 + (lane & 15);
            bf16x8 bk0 = *(const bf16x8*)(Kbase + (size_t)krow * 128 + (lane >> 4) * 16);
            bf16x8 bk1 = *(const bf16x8*)(Kbase + (size_t)krow * 128 + 64 + (lane >> 4) * 16);
            f32x4 s = {0.f, 0.f, 0.f, 0.f};
            s = __builtin_amdgcn_mfma_f32_16x16x32_bf16(aq0, bk0, s, 0, 0, 0);
            s = __builtin_amdgcn_mfma_f32_16x16x32_bf16(aq1, bk1, s, 0, 0, 0);
            const float mk = mask[b * SS + krow];
            #pragma unroll
            for (int r = 0; r < 4; ++r)
                zr[r] += __expf(s[r] * 0.125f + mk);
        }
    }
    float invz1[4];
    #pragma unroll
    for (int r = 0; r < 4; ++r) {
        float z = zr[r];
        z += __shfl_xor(z, 1); z += __shfl_xor(z, 2);
        z += __shfl_xor(z, 4); z += __shfl_xor(z, 8);
        invz1[r] = 1.0f / z;
    }

    // ---------------- pass 2 ----------------
    f32x4 pacc[4];
    const f32x4 zz = {0.f, 0.f, 0.f, 0.f};
    pacc[0] = zz; pacc[1] = zz; pacc[2] = zz; pacc[3] = zz;
    float z2acc[4] = {0.f, 0.f, 0.f, 0.f};   // B-role: 4 heads of hgrp

    for (int kt = 0; kt < 16; ++kt) {
        // ---- phase A: p1 tile into own slice ----
        #pragma unroll
        for (int nf = 0; nf < 4; ++nf) {
            const int krow = kt * 64 + nf * 16 + (lane & 15);
            bf16x8 bk0 = *(const bf16x8*)(Kbase + (size_t)krow * 128 + (lane >> 4) * 16);
            bf16x8 bk1 = *(const bf16x8*)(Kbase + (size_t)krow * 128 + 64 + (lane >> 4) * 16);
            f32x4 s = {0.f, 0.f, 0.f, 0.f};
            s = __builtin_amdgcn_mfma_f32_16x16x32_bf16(aq0, bk0, s, 0, 0, 0);
            s = __builtin_amdgcn_mfma_f32_16x16x32_bf16(aq1, bk1, s, 0, 0, 0);
            const float mk = mask[b * SS + krow];
            const int kcl = nf * 16 + (lane & 15);
            #pragma unroll
            for (int r = 0; r < 4; ++r) {
                const int qr = (lane >> 4) * 4 + r;
                const float p1 = __expf(s[r] * 0.125f + mk) * invz1[r];
                *(unsigned short*)(Pbuf + w * 2048 + ((qr * 128 + kcl * 2) ^ ((qr & 7) << 4))) =
                    (unsigned short)f2bf(p1);
            }
        }
        __syncthreads();

        // ---- phase B: conv + e2 (coop layout, prev direct from global) ----
        float4 pvv[12];
        #pragma unroll
        for (int i = 0; i < 12; ++i)
            pvv[i] = *(const float4*)&prev[(((size_t)(b * HH + i)) * SS + q0 + qB) * SS + kt * 64 + k4 * 4];
        #pragma unroll
        for (int j = 0; j < 4; ++j) {
            const int h = hgrp * 4 + j;
            char* pp = Pbuf + ((h * 2048 + qB * 128 + k4 * 8) ^ ((qB & 7) << 4));
            uint2 pu = *(uint2*)pp;
            float m0 = cbs[h], m1 = cbs[h], m2 = cbs[h], m3 = cbs[h];
            #pragma unroll
            for (int i = 0; i < 12; ++i) {
                const float cwi = cws[h * 12 + i];
                m0 = fmaf(cwi, pvv[i].x, m0);
                m1 = fmaf(cwi, pvv[i].y, m1);
                m2 = fmaf(cwi, pvv[i].z, m2);
                m3 = fmaf(cwi, pvv[i].w, m3);
            }
            const float e0 = __expf(0.5f * (m0 + bf2f(pu.x & 0xFFFFu)));
            const float e1 = __expf(0.5f * (m1 + bf2f(pu.x >> 16)));
            const float e2 = __expf(0.5f * (m2 + bf2f(pu.y & 0xFFFFu)));
            const float e3 = __expf(0.5f * (m3 + bf2f(pu.y >> 16)));
            z2acc[j] += (e0 + e1) + (e2 + e3);
            uint2 ou;
            ou.x = f2bf(e0) | (f2bf(e1) << 16);
            ou.y = f2bf(e2) | (f2bf(e3) << 16);
            *(uint2*)pp = ou;
        }
        __syncthreads();

        // ---- phase C: PV ----
        #pragma unroll
        for (int ks = 0; ks < 2; ++ks) {
            const int q = lane & 15;
            bf16x8 pa = *(const bf16x8*)(Pbuf + w * 2048 +
                          ((q * 128 + ks * 64 + (lane >> 4) * 16) ^ ((q & 7) << 4)));
            #pragma unroll
            for (int nfd = 0; nfd < 4; ++nfd) {
                const int vrow = nfd * 16 + (lane & 15);
                bf16x8 vb = *(const bf16x8*)(Vbase + (size_t)vrow * 2048 + kt * 128 +
                                             ks * 64 + (lane >> 4) * 16);
                pacc[nfd] = __builtin_amdgcn_mfma_f32_16x16x32_bf16(pa, vb, pacc[nfd], 0, 0, 0);
            }
        }
        // no barrier needed: after this, slice w touched only by wave w (phase A next kt)
    }

    // ---- z2 exchange ----
    #pragma unroll
    for (int j = 0; j < 4; ++j) {
        float z = z2acc[j];
        z += __shfl_xor(z, 1); z += __shfl_xor(z, 2);
        z += __shfl_xor(z, 4); z += __shfl_xor(z, 8);
        z2acc[j] = z;
    }
    if ((tid & 15) == 0) {
        #pragma unroll
        for (int j = 0; j < 4; ++j)
            z2buf[hgrp * 4 + j][qB] = z2acc[j];
    }
    __syncthreads();

    // ---- divide, per-wave repack through own slice, coalesced store ----
    #pragma unroll
    for (int nfd = 0; nfd < 4; ++nfd) {
        const int d = nfd * 16 + (lane & 15);
        #pragma unroll
        for (int r = 0; r < 4; ++r) {
            const int qr = (lane >> 4) * 4 + r;
            const float o = pacc[nfd][r] / z2buf[w][qr];
            *(unsigned short*)(Pbuf + w * 2048 + ((qr * 128 + d * 2) ^ ((qr & 7) << 4))) =
                (unsigned short)f2bf(o);
        }
    }
    __syncthreads();
    {
        const int qq = lane >> 2, c32 = (lane & 3) * 32;
        const int sw = (qq & 7) << 4;
        uint4 lo = *(uint4*)(Pbuf + w * 2048 + ((qq * 128 + c32) ^ sw));
        uint4 hi = *(uint4*)(Pbuf + w * 2048 + ((qq * 128 + c32 + 16) ^ sw));
        char* dst = (char*)ctx + (((size_t)(b * SS + q0 + qq)) * DD + w * DHH) * 2 + c32;
        *(uint4*)dst = lo; *(uint4*)(dst + 16) = hi;
    }
}

// ======================================================================
// out-projection: ctx bf16 @ Wo_t -> gout fp32 (+bo)
// ======================================================================
__global__ __launch_bounds__(256)
void o_gemm_kernel(const unsigned short* __restrict__ ctx, const unsigned short* __restrict__ WtO,
                   const float* __restrict__ bo, float* __restrict__ gout)
{
    __shared__ __align__(16) char smem[16384];
    char* As = smem;
    char* Bs = smem + 8192;
    const int tid = threadIdx.x;
    const int m0 = blockIdx.x * 64;
    const int n0 = blockIdx.y * 64;

    f32x4 acc[2][2];
    const f32x4 z4 = {0.f, 0.f, 0.f, 0.f};
    acc[0][0] = z4; acc[0][1] = z4; acc[1][0] = z4; acc[1][1] = z4;

    gemm_core64((const char*)ctx + (size_t)m0 * 1536,
                (const char*)WtO + (size_t)n0 * 1536, As, Bs, tid, acc);

    const int lane = tid & 63;
    const int wr = (tid >> 7) & 1, wc = (tid >> 6) & 1;
    #pragma unroll
    for (int mi = 0; mi < 2; ++mi)
        #pragma unroll
        for (int ni = 0; ni < 2; ++ni) {
            const int ncol = wc * 32 + ni * 16 + (lane & 15);
            const float bb = bo[n0 + ncol];
            #pragma unroll
            for (int r = 0; r < 4; ++r) {
                const int row = wr * 32 + mi * 16 + (lane >> 4) * 4 + r;
                *(float*)(smem + ((row * 256 + ncol * 4) ^ ((row & 7) << 4))) =
                    acc[mi][ni][r] + bb;
            }
        }
    __syncthreads();
    {
        const int row = tid >> 2, c64 = (tid & 3) * 64;
        const int sw = (row & 7) << 4;
        float4 v[4];
        #pragma unroll
        for (int j = 0; j < 4; ++j)
            v[j] = *(float4*)(smem + ((row * 256 + c64 + j * 16) ^ sw));
        float* dst = gout + (size_t)(m0 + row) * DD + n0 + (tid & 3) * 16;
        #pragma unroll
        for (int j = 0; j < 4; ++j)
            *(float4*)(dst + j * 4) = v[j];
    }
}

// ======================================================================
// Residual + LayerNorm (fp32)
// ======================================================================
__global__ __launch_bounds__(256)
void ln_kernel(const float* __restrict__ go, const float* __restrict__ hid,
               const float* __restrict__ lw, const float* __restrict__ lb,
               float* __restrict__ out)
{
    const int row = blockIdx.x;
    const int tid = threadIdx.x;
    const int lane = tid & 63, wave = tid >> 6;
    __shared__ float wsum[4], wsq[4];

    float x[3];
    float ssum = 0.f, ssq = 0.f;
    #pragma unroll
    for (int j = 0; j < 3; ++j) {
        const int n = tid + j * 256;
        const float v = go[(size_t)row * DD + n] + hid[(size_t)row * DD + n];
        x[j] = v; ssum += v; ssq += v * v;
    }
    for (int off = 32; off; off >>= 1) {
        ssum += __shfl_xor(ssum, off);
        ssq  += __shfl_xor(ssq, off);
    }
    if (lane == 0) { wsum[wave] = ssum; wsq[wave] = ssq; }
    __syncthreads();
    const float tsum = wsum[0] + wsum[1] + wsum[2] + wsum[3];
    const float tsq  = wsq[0] + wsq[1] + wsq[2] + wsq[3];
    const float mean = tsum * (1.0f / 768.0f);
    const float var  = tsq * (1.0f / 768.0f) - mean * mean;
    const float rstd = rsqrtf(var + 1e-12f);
    #pragma unroll
    for (int j = 0; j < 3; ++j) {
        const int n = tid + j * 256;
        out[(size_t)row * DD + n] = lw[n] * ((x[j] - mean) * rstd) + lb[n];
    }
}

extern "C" void kernel_launch(void* const* d_in, const int* in_sizes, int n_in,
                              void* d_out, int out_size, void* d_ws, size_t ws_size,
                              hipStream_t stream)
{
    const float* hidden = (const float*)d_in[0];
    const float* mask   = (const float*)d_in[1];
    const float* prev   = (const float*)d_in[2];
    const float* Wq = (const float*)d_in[3];  const float* bq = (const float*)d_in[4];
    const float* Wk = (const float*)d_in[5];  const float* bk = (const float*)d_in[6];
    const float* Wv = (const float*)d_in[7];  const float* bv = (const float*)d_in[8];
    const float* cw = (const float*)d_in[9];  const float* cb = (const float*)d_in[10];
    const float* Wo = (const float*)d_in[11]; const float* bo = (const float*)d_in[12];
    const float* lw = (const float*)d_in[13]; const float* lb = (const float*)d_in[14];
    float* out = (float*)d_out;

    char* w = (char*)d_ws;
    unsigned short* hbf = (unsigned short*)(w);              //  6 MB   [0, 6291456)
    unsigned short* Wt  = (unsigned short*)(w + 6291456);    //  4.5 MB
    unsigned short* Qb  = (unsigned short*)(w + 11010048);   //  6 MB
    unsigned short* Kb  = (unsigned short*)(w + 17301504);   //  6 MB
    unsigned short* Vtb = (unsigned short*)(w + 23592960);   //  6 MB  (end 29884416)
    unsigned short* ctx = hbf;                               // alias (hbf dead after QKV)
    float* gout = (float*)(w + 11010048);                    // alias Qb+Kb (12 MB, dead after fused)

    dim3 blk(256);
    cvt_hidden_kernel<<<dim3(1536), blk, 0, stream>>>(hidden, hbf);
    transpose_w_kernel<<<dim3(24, 24, 4), blk, 0, stream>>>(Wq, Wk, Wv, Wo, Wt);
    qkv_gemm_kernel<<<dim3(64, 36), blk, 0, stream>>>(hbf, Wt, bq, bk, bv, Qb, Kb, Vtb);
    fused_attn_kernel<<<dim3(256), dim3(768), 0, stream>>>(Qb, Kb, Vtb, prev, mask, cw, cb, ctx);
    o_gemm_kernel<<<dim3(64, 12), blk, 0, stream>>>(ctx, Wt + (size_t)3 * DD * DD, bo, gout);
    ln_kernel<<<dim3(4096), blk, 0, stream>>>(gout, hidden, lw, lb, out);
}